// Round 7
// baseline (325.118 us; speedup 1.0000x reference)
//
#include <hip/hip_runtime.h>
#include <hip/hip_bf16.h>

#define FEAT 128
#define OUTF 64
#define BBITS 9           // nodes per bucket = 512
#define NPB (1 << BBITS)
#define NBIN 256          // level-1 hist arrays (nbuck = 196 <= 256)
#define BCAP 10240        // mean 8163 edges/bucket, sigma ~90 -> +23 sigma
#define L1_CHUNK 4096
#define EPT 16            // edges per thread in level1 (L1_CHUNK / 256)

typedef __attribute__((ext_vector_type(8))) short short8;   // 8 bf16 = 4 VGPRs (MFMA A/B frag)
typedef __attribute__((ext_vector_type(4))) float floatx4;  // MFMA C/D frag (nt-store safe)

// ---- bf16 helpers (packed pair in a 32-bit word, little-endian: lo16 = even elem) ----
__device__ inline float bflo(unsigned p) { union { unsigned u; float f; } c; c.u = p << 16;        return c.f; }
__device__ inline float bfhi(unsigned p) { union { unsigned u; float f; } c; c.u = p & 0xffff0000u; return c.f; }
__device__ inline unsigned rne16(float v) {   // fp32 -> bf16 bits, round-nearest-even
    union { float f; unsigned u; } c; c.f = v;
    return (c.u + 0x7fffu + ((c.u >> 16) & 1u)) >> 16;
}
__device__ inline unsigned pack2bf(float a, float b) { return rne16(a) | (rne16(b) << 16); }

// ---------------- dtype sniff + bcursor zero + W conversion (one launch) ----------------
// flags[0]=1 iff x is packed bf16; flags[1]=1 iff edge_index is int64; flags[2]=1 iff W is packed bf16.
__global__ void sniff_convw(const unsigned* __restrict__ x, const unsigned* __restrict__ ei,
                            const void* __restrict__ Wv, unsigned* __restrict__ Wp,
                            int* __restrict__ flags, int* __restrict__ bcursor, int nbuck) {
    __shared__ int s_x, s_z, s_w;
    int t = threadIdx.x;
    if (t == 0) { s_x = 0; s_z = 0; s_w = 0; }
    __syncthreads();
    if (t < nbuck) bcursor[t] = 0;
    unsigned lx = x[t] & 0xffffu;
    unsigned ex = (lx >> 7) & 0xffu;
    if (lx == 0u || (ex >= 100u && ex <= 140u)) atomicAdd(&s_x, 1);
    unsigned lw = ((const unsigned*)Wv)[t] & 0xffffu;
    unsigned ew = (lw >> 7) & 0xffu;
    if (lw == 0u || (ew >= 100u && ew <= 140u)) atomicAdd(&s_w, 1);
    if (ei[2 * t + 1] == 0u) atomicAdd(&s_z, 1);
    __syncthreads();
    int wbf = (s_w >= 230);
    if (t == 0) {
        flags[0] = (s_x >= 230) ? 1 : 0;
        flags[1] = (s_z >= 250) ? 1 : 0;
        flags[2] = wbf;
    }
    // convert W -> packed bf16 (64x128 = 4096 pairs, 16 per thread)
    for (int idx = t; idx < OUTF * FEAT / 2; idx += 256) {
        if (wbf) {
            Wp[idx] = ((const unsigned*)Wv)[idx];
        } else {
            float2 v = ((const float2*)Wv)[idx];
            Wp[idx] = pack2bf(v.x, v.y);
        }
    }
}

__device__ inline int edge_row(const int* __restrict__ ei, int E, int e, int w64) {
    return w64 ? ei[2 * e] : ei[e];
}
__device__ inline int edge_col(const int* __restrict__ ei, int E, int e, int w64) {
    return w64 ? ei[2 * (E + e)] : ei[E + e];
}

// ---------------- CSR build: two-level, LDS-binned ----------------
// level 1: chunk of 4096 edges per block, loaded ONCE into registers (16/thread,
// fully unrolled -> static indices stay in VGPRs), then LDS bin-sort by (dst>>9)
// -> dense coalesced copy-out. packed word: (dst_local[9] << 17) | src_row[17].
__global__ void __launch_bounds__(256)
level1_bin(const int* __restrict__ ei, int E, int* __restrict__ bcursor,
           unsigned* __restrict__ bucket, const int* __restrict__ flags, int nbuck) {
    __shared__ unsigned elds[L1_CHUNK];
    __shared__ unsigned char ebin[L1_CHUNK];
    __shared__ int hist[NBIN], binstart[NBIN], cur[NBIN], ticket[NBIN];
    int t = threadIdx.x;
    int base = blockIdx.x * L1_CHUNK;
    int cnt = min(E - base, L1_CHUNK);
    int w64 = flags[1];

    // single global read of this chunk's edges into registers
    unsigned wd[EPT];
    int bn[EPT];
#pragma unroll
    for (int j = 0; j < EPT; ++j) {
        int k = t + 256 * j;
        if (k < cnt) {
            int e = base + k;
            int c = edge_col(ei, E, e, w64);
            int r = edge_row(ei, E, e, w64);
            wd[j] = ((unsigned)(c & (NPB - 1)) << 17) | (unsigned)r;
            bn[j] = c >> BBITS;
        } else {
            bn[j] = -1;
        }
    }

    hist[t] = 0;
    __syncthreads();
#pragma unroll
    for (int j = 0; j < EPT; ++j)
        if (bn[j] >= 0) atomicAdd(&hist[bn[j]], 1);
    __syncthreads();
    binstart[t] = hist[t];
    __syncthreads();
    for (int off = 1; off < NBIN; off <<= 1) {
        int v = (t >= off) ? binstart[t - off] : 0;
        __syncthreads();
        binstart[t] += v;
        __syncthreads();
    }
    { int ex = binstart[t] - hist[t]; cur[t] = ex; binstart[t] = ex; }
    __syncthreads();
#pragma unroll
    for (int j = 0; j < EPT; ++j) {
        if (bn[j] >= 0) {
            int pos = atomicAdd(&cur[bn[j]], 1);
            elds[pos] = wd[j];
            ebin[pos] = (unsigned char)bn[j];
        }
    }
    __syncthreads();
    {
        int h = hist[t];
        ticket[t] = (t < nbuck && h > 0) ? atomicAdd(&bcursor[t], h) : 0;
    }
    __syncthreads();
    for (int k = t; k < cnt; k += 256) {
        unsigned w = elds[k];
        int b = ebin[k];
        int dst = ticket[b] + (k - binstart[b]);
        if (dst < BCAP) bucket[(size_t)b * BCAP + dst] = w;
    }
}

// level 2 + projection, fused: one 512-thread workgroup per bucket (512 nodes).
// Phase A (CSR): integrated prefix base; LDS hist -> offsets+dinv; LDS cursor
// scatter into contiguous csr window. Phase B (projection): the SAME block
// projects its own 512 nodes: y[node][64] = dinv[node] * (x_row . W_col) via
// MFMA, dinv read from LDS. No cross-block dependency; fills the latency slack
// of the 196-block (77% CU) grid and kills the standalone project launch.
__global__ void __launch_bounds__(512)
level2_csr_project(const unsigned* __restrict__ bucket, const int* __restrict__ bcursor,
                   int nbuck, int n,
                   const void* __restrict__ xv, const unsigned* __restrict__ Wp,
                   int* __restrict__ offsets, float* __restrict__ dinv, int* __restrict__ csr,
                   unsigned* __restrict__ y, const int* __restrict__ flags) {
    __shared__ int hist[NPB];       // 512
    __shared__ int nodeoff[NPB];
    __shared__ int sdata[NPB];
    __shared__ float sdinv[NPB];
    __shared__ unsigned xs[2][16][68];   // two 16-row x tiles (stride 68: 16B-aligned, 2-way banks free)
    int b = blockIdx.x;
    int t = threadIdx.x;            // 0..511, owns node nbeg+t in phase A
    int nbeg = b << BBITS;
    int cnt = min(bcursor[b], BCAP);

    // base = sum_{j<b} min(bcursor[j], BCAP)
    sdata[t] = (t < b && t < nbuck) ? min(bcursor[t], BCAP) : 0;
    __syncthreads();
    for (int off = 256; off > 0; off >>= 1) {
        if (t < off) sdata[t] += sdata[t + off];
        __syncthreads();
    }
    int base = sdata[0];
    __syncthreads();
    if (b == nbuck - 1 && t == 0) offsets[n] = base + cnt;   // grand total

    const unsigned* __restrict__ bk = bucket + (size_t)b * BCAP;

    hist[t] = 0;
    __syncthreads();
    for (int e = t; e < cnt; e += 512) atomicAdd(&hist[bk[e] >> 17], 1);
    __syncthreads();
    int h = hist[t];
    sdata[t] = h;
    __syncthreads();
    for (int off = 1; off < NPB; off <<= 1) {
        int v = (t >= off) ? sdata[t - off] : 0;
        __syncthreads();
        sdata[t] += v;
        __syncthreads();
    }
    int p = base + sdata[t] - h;                 // exclusive offset for node nbeg+t
    nodeoff[t] = p;
    float dv = rsqrtf((float)(h + 1));           // +1 self-loop; deg>=1 always
    sdinv[t] = dv;
    int node = nbeg + t;
    if (node < n) {
        offsets[node] = p;
        dinv[node] = dv;
    }
    __syncthreads();
    hist[t] = 0;                                 // reuse as cursors
    __syncthreads();
    for (int e = t; e < cnt; e += 512) {
        unsigned w = bk[e];
        int l = w >> 17;
        int pos = nodeoff[l] + atomicAdd(&hist[l], 1);
        csr[pos] = (int)(w & 0x1FFFFu);
    }

    // ---------------- phase B: project this bucket's 512 nodes ----------------
    // 2 groups of 256 threads; group g handles tiles (2*it + g), it = 0..15.
    // Per tile: stage 16 x-rows -> bf16 LDS, then 4 waves do 16x16 MFMA tiles
    // (A = W rows / outcols wave4*16..+15, B = node rows; m89-verified C/D layout).
    int fx = flags[0];
    int grp  = t >> 8;               // 0/1
    int tt   = t & 255;
    int wave4 = tt >> 6;             // outcol tile 0..3
    int lane = tt & 63;
    int m16  = lane & 15;
    int quad = lane >> 4;
    const uint4* __restrict__ Arow = (const uint4*)(Wp + (size_t)(wave4 * 16 + m16) * 64);

    for (int it = 0; it < 16; ++it) {
        int tile = it * 2 + grp;             // 0..31
        int r0 = tile << 4;                  // node offset within bucket
        __syncthreads();                     // xs free to overwrite (both groups in lockstep)
        for (int idx = tt; idx < 16 * 64; idx += 256) {
            int r = idx >> 6, q = idx & 63;
            int nd = min(nbeg + r0 + r, n - 1);
            unsigned w;
            if (fx) {
                w = ((const unsigned*)xv)[(size_t)nd * 64 + q];
            } else {
                float2 v = ((const float2*)xv)[(size_t)nd * 64 + q];
                w = pack2bf(v.x, v.y);
            }
            xs[grp][r][q] = w;
        }
        __syncthreads();
        floatx4 acc = {0.f, 0.f, 0.f, 0.f};
#pragma unroll
        for (int kc = 0; kc < 4; ++kc) {
            union { uint4 u; short8 s; } a, bb;
            a.u = Arow[kc * 4 + quad];
            bb.u = *(const uint4*)&xs[grp][m16][(kc * 4 + quad) * 4];
            acc = __builtin_amdgcn_mfma_f32_16x16x32_bf16(a.s, bb.s, acc, 0, 0, 0);
        }
        int nd = nbeg + r0 + m16;
        if (nd < n) {
            float di = sdinv[r0 + m16];
            uint2 w;
            w.x = pack2bf(di * acc[0], di * acc[1]);
            w.y = pack2bf(di * acc[2], di * acc[3]);
            *(uint2*)(y + (size_t)nd * 32 + wave4 * 8 + quad * 2) = w;  // outcols wave4*16+quad*4..+3
        }
    }
}

// ---------------- propagation on 64-feat pre-scaled rows (R5-measured-best shape) ----------------
// g[j] = dinv[j]*h[j] is stored; per hop: sum_{j in N(i)+self} g[j], then
//   mode 0: g_out = di^2 * sum (bf16)      mode 1: h_out = di*sum + b (fp32 to d_out, nt)
// wave = 1 node; 16 lanes = 1 edge (uint2/lane = 128B row) -> 4 edge-groups/wave,
// unroll x4 => 16 gathers in flight.
__global__ void __launch_bounds__(256)
propagate64(const unsigned* __restrict__ hin, const int* __restrict__ offsets,
            const int* __restrict__ csr, const float* __restrict__ dinv,
            void* __restrict__ outv, const void* __restrict__ bv,
            int n, int mode, const int* __restrict__ flags) {
    int wave = threadIdx.x >> 6;
    int lane = threadIdx.x & 63;
    int g    = lane >> 4;            // edge-group 0..3
    int s    = lane & 15;            // dword pair within row (dwords 2s, 2s+1 = feats 4s..4s+3)
    int i = blockIdx.x * 4 + wave;
    if (i >= n) return;
    int beg = offsets[i];
    int end = offsets[i + 1];
    // self row: issue early, same addr across groups (broadcast-friendly)
    uint2 ps = *(const uint2*)(hin + (size_t)i * 32 + 2 * s);
    float a0 = 0.f, a1 = 0.f, a2 = 0.f, a3 = 0.f;
    int k = beg + g;
    for (; k + 12 < end; k += 16) {          // 16 edges per wave per round
        int s0 = csr[k], s1 = csr[k + 4], s2 = csr[k + 8], s3 = csr[k + 12];
        uint2 p0 = *(const uint2*)(hin + (size_t)s0 * 32 + 2 * s);
        uint2 p1 = *(const uint2*)(hin + (size_t)s1 * 32 + 2 * s);
        uint2 p2 = *(const uint2*)(hin + (size_t)s2 * 32 + 2 * s);
        uint2 p3 = *(const uint2*)(hin + (size_t)s3 * 32 + 2 * s);
        a0 += bflo(p0.x); a1 += bfhi(p0.x); a2 += bflo(p0.y); a3 += bfhi(p0.y);
        a0 += bflo(p1.x); a1 += bfhi(p1.x); a2 += bflo(p1.y); a3 += bfhi(p1.y);
        a0 += bflo(p2.x); a1 += bfhi(p2.x); a2 += bflo(p2.y); a3 += bfhi(p2.y);
        a0 += bflo(p3.x); a1 += bfhi(p3.x); a2 += bflo(p3.y); a3 += bfhi(p3.y);
    }
    for (; k < end; k += 4) {
        int sj = csr[k];
        uint2 p = *(const uint2*)(hin + (size_t)sj * 32 + 2 * s);
        a0 += bflo(p.x); a1 += bfhi(p.x); a2 += bflo(p.y); a3 += bfhi(p.y);
    }
    if (g == 0) {                    // self-loop term counted exactly once
        a0 += bflo(ps.x); a1 += bfhi(ps.x); a2 += bflo(ps.y); a3 += bfhi(ps.y);
    }
    // reduce across the 4 edge-groups
    a0 += __shfl_xor(a0, 16); a1 += __shfl_xor(a1, 16);
    a2 += __shfl_xor(a2, 16); a3 += __shfl_xor(a3, 16);
    a0 += __shfl_xor(a0, 32); a1 += __shfl_xor(a1, 32);
    a2 += __shfl_xor(a2, 32); a3 += __shfl_xor(a3, 32);
    if (g == 0) {
        float di = dinv[i];
        if (mode == 0) {
            float sc = di * di;
            uint2 w;
            w.x = pack2bf(sc * a0, sc * a1);
            w.y = pack2bf(sc * a2, sc * a3);
            *(uint2*)((unsigned*)outv + (size_t)i * 32 + 2 * s) = w;
        } else {
            float b0, b1, b2, b3;
            if (flags[2]) {
                const unsigned short* bp = (const unsigned short*)bv;
                union { unsigned u; float f; } c0, c1, c2, c3;
                c0.u = (unsigned)bp[4 * s]     << 16;
                c1.u = (unsigned)bp[4 * s + 1] << 16;
                c2.u = (unsigned)bp[4 * s + 2] << 16;
                c3.u = (unsigned)bp[4 * s + 3] << 16;
                b0 = c0.f; b1 = c1.f; b2 = c2.f; b3 = c3.f;
            } else {
                float4 bb = ((const float4*)bv)[s];
                b0 = bb.x; b1 = bb.y; b2 = bb.z; b3 = bb.w;
            }
            floatx4 o;
            o[0] = di * a0 + b0;
            o[1] = di * a1 + b1;
            o[2] = di * a2 + b2;
            o[3] = di * a3 + b3;
            // final output is never re-read: keep it out of L2 while this hop gathers
            // (ext-vector type: __builtin_nontemporal_store rejects HIP_vector_type float4)
            __builtin_nontemporal_store(o, (floatx4*)outv + (size_t)i * 16 + s);
        }
    }
}

// ---------------- launch ----------------

extern "C" void kernel_launch(void* const* d_in, const int* in_sizes, int n_in,
                              void* d_out, int out_size, void* d_ws, size_t ws_size,
                              hipStream_t stream) {
    const void* x  = d_in[0];
    const int*  ei = (const int*)d_in[1];
    const void* W  = d_in[2];
    const void* b  = d_in[3];
    float* out = (float*)d_out;              // fp32 output

    const int n = in_sizes[0] / FEAT;        // 100000
    const int E = in_sizes[1] / 2;           // 1600000
    const int nbuck = (n + NPB - 1) >> BBITS;   // 196 <= 256

    // workspace layout (256B-aligned slabs)
    char* ws = (char*)d_ws;
    size_t off = 0;
    auto alloc = [&](size_t bytes) {
        void* p = ws + off;
        off = (off + bytes + 255) & ~(size_t)255;
        return p;
    };
    unsigned* y       = (unsigned*)alloc((size_t)n * 32 * sizeof(unsigned));  // 64-feat bf16 rows
    unsigned* hA      = (unsigned*)alloc((size_t)n * 32 * sizeof(unsigned));
    unsigned* Wp      = (unsigned*)alloc((size_t)OUTF * (FEAT / 2) * sizeof(unsigned));
    int*      offsets = (int*)alloc((size_t)(n + 1) * sizeof(int));
    float*    dinv    = (float*)alloc((size_t)n * sizeof(float));
    int*      csr     = (int*)alloc((size_t)E * sizeof(int));
    unsigned* bucket  = (unsigned*)alloc((size_t)nbuck * BCAP * sizeof(unsigned));
    int*      bcursor = (int*)alloc((size_t)nbuck * sizeof(int));
    int*      flags   = (int*)alloc(3 * sizeof(int));

    // dtype sniff + bcursor zero + W->bf16 (one launch; graph-safe)
    sniff_convw<<<1, 256, 0, stream>>>((const unsigned*)x, (const unsigned*)ei,
                                       W, Wp, flags, bcursor, nbuck);

    // CSR build: LDS-binned two-level; level2 fuses the per-bucket projection
    level1_bin<<<(E + L1_CHUNK - 1) / L1_CHUNK, 256, 0, stream>>>(ei, E, bcursor, bucket,
                                                                  flags, nbuck);
    level2_csr_project<<<nbuck, 512, 0, stream>>>(bucket, bcursor, nbuck, n,
                                                  x, Wp, offsets, dinv, csr, y, flags);

    // 3 hops on 64-feat rows: y -> hA -> y -> out (last hop adds bias, writes fp32 nt)
    const int propBlocks = (n + 3) / 4;      // 4 waves/block, 1 node/wave
    propagate64<<<propBlocks, 256, 0, stream>>>(y,  offsets, csr, dinv, hA,  b, n, 0, flags);
    propagate64<<<propBlocks, 256, 0, stream>>>(hA, offsets, csr, dinv, y,   b, n, 0, flags);
    propagate64<<<propBlocks, 256, 0, stream>>>(y,  offsets, csr, dinv, out, b, n, 1, flags);
}

// Round 8
// 309.181 us; speedup vs baseline: 1.0515x; 1.0515x over previous
//
#include <hip/hip_runtime.h>
#include <hip/hip_bf16.h>

#define FEAT 128
#define OUTF 64
#define BBITS 9           // nodes per bucket = 512
#define NPB (1 << BBITS)
#define NBIN 256          // level-1 hist arrays (nbuck = 196 <= 256)
#define BCAP 10240        // mean 8163 edges/bucket, sigma ~90 -> +23 sigma
#define L1_CHUNK 4096
#define EPT 16            // edges per thread in level1 (L1_CHUNK / 256)
#define EPT2 20           // edges per thread in level2 (BCAP / 512)

typedef __attribute__((ext_vector_type(8))) short short8;   // 8 bf16 = 4 VGPRs (MFMA A/B frag)
typedef __attribute__((ext_vector_type(4))) float floatx4;  // MFMA C/D frag (nt-store safe)

// ---- bf16 helpers (packed pair in a 32-bit word, little-endian: lo16 = even elem) ----
__device__ inline float bflo(unsigned p) { union { unsigned u; float f; } c; c.u = p << 16;        return c.f; }
__device__ inline float bfhi(unsigned p) { union { unsigned u; float f; } c; c.u = p & 0xffff0000u; return c.f; }
__device__ inline unsigned rne16(float v) {   // fp32 -> bf16 bits, round-nearest-even
    union { float f; unsigned u; } c; c.f = v;
    return (c.u + 0x7fffu + ((c.u >> 16) & 1u)) >> 16;
}
__device__ inline unsigned pack2bf(float a, float b) { return rne16(a) | (rne16(b) << 16); }

// ---------------- dtype sniff + bcursor zero + W conversion (one launch) ----------------
// flags[0]=1 iff x is packed bf16; flags[1]=1 iff edge_index is int64; flags[2]=1 iff W is packed bf16.
__global__ void sniff_convw(const unsigned* __restrict__ x, const unsigned* __restrict__ ei,
                            const void* __restrict__ Wv, unsigned* __restrict__ Wp,
                            int* __restrict__ flags, int* __restrict__ bcursor, int nbuck) {
    __shared__ int s_x, s_z, s_w;
    int t = threadIdx.x;
    if (t == 0) { s_x = 0; s_z = 0; s_w = 0; }
    __syncthreads();
    if (t < nbuck) bcursor[t] = 0;
    unsigned lx = x[t] & 0xffffu;
    unsigned ex = (lx >> 7) & 0xffu;
    if (lx == 0u || (ex >= 100u && ex <= 140u)) atomicAdd(&s_x, 1);
    unsigned lw = ((const unsigned*)Wv)[t] & 0xffffu;
    unsigned ew = (lw >> 7) & 0xffu;
    if (lw == 0u || (ew >= 100u && ew <= 140u)) atomicAdd(&s_w, 1);
    if (ei[2 * t + 1] == 0u) atomicAdd(&s_z, 1);
    __syncthreads();
    int wbf = (s_w >= 230);
    if (t == 0) {
        flags[0] = (s_x >= 230) ? 1 : 0;
        flags[1] = (s_z >= 250) ? 1 : 0;
        flags[2] = wbf;
    }
    // convert W -> packed bf16 (64x128 = 4096 pairs, 16 per thread)
    for (int idx = t; idx < OUTF * FEAT / 2; idx += 256) {
        if (wbf) {
            Wp[idx] = ((const unsigned*)Wv)[idx];
        } else {
            float2 v = ((const float2*)Wv)[idx];
            Wp[idx] = pack2bf(v.x, v.y);
        }
    }
}

__device__ inline int edge_row(const int* __restrict__ ei, int E, int e, int w64) {
    return w64 ? ei[2 * e] : ei[e];
}
__device__ inline int edge_col(const int* __restrict__ ei, int E, int e, int w64) {
    return w64 ? ei[2 * (E + e)] : ei[E + e];
}

// ---------------- CSR build: two-level, LDS-binned ----------------
// level 1: chunk of 4096 edges per block, loaded ONCE into registers (16/thread,
// fully unrolled -> VGPRs), LDS bin-sort by (dst>>9), wave-shfl scan (1 barrier
// instead of 16), no ebin byte array (R7 lesson: cut LDS ops + barriers), dense
// wave-per-bin coalesced copy-out. packed word: (dst_local[9] << 17) | src[17].
__global__ void __launch_bounds__(256)
level1_bin(const int* __restrict__ ei, int E, int* __restrict__ bcursor,
           unsigned* __restrict__ bucket, const int* __restrict__ flags, int nbuck) {
    __shared__ unsigned elds[L1_CHUNK];
    __shared__ int hist[NBIN], binstart[NBIN], cur[NBIN], ticket[NBIN];
    __shared__ int wsum[4];
    int t = threadIdx.x;
    int lane = t & 63, wav = t >> 6;
    int base = blockIdx.x * L1_CHUNK;
    int cnt = min(E - base, L1_CHUNK);
    int w64 = flags[1];

    // single global read of this chunk's edges into registers
    unsigned wd[EPT];
    int bn[EPT];
#pragma unroll
    for (int j = 0; j < EPT; ++j) {
        int k = t + 256 * j;
        if (k < cnt) {
            int e = base + k;
            int c = edge_col(ei, E, e, w64);
            int r = edge_row(ei, E, e, w64);
            wd[j] = ((unsigned)(c & (NPB - 1)) << 17) | (unsigned)r;
            bn[j] = c >> BBITS;
        } else {
            bn[j] = -1;
        }
    }

    hist[t] = 0;
    __syncthreads();
#pragma unroll
    for (int j = 0; j < EPT; ++j)
        if (bn[j] >= 0) atomicAdd(&hist[bn[j]], 1);
    __syncthreads();

    // exclusive scan of hist[256]: shfl within wave, 1 barrier across 4 waves
    int h = hist[t];
    int v = h;
    for (int off = 1; off < 64; off <<= 1) {
        int u = __shfl_up(v, off);
        if (lane >= off) v += u;
    }
    if (lane == 63) wsum[wav] = v;
    __syncthreads();
    int wbase = 0;
    for (int w2 = 0; w2 < wav; ++w2) wbase += wsum[w2];
    int ex = wbase + v - h;              // exclusive prefix
    binstart[t] = ex;
    cur[t] = ex;
    __syncthreads();

    // scatter into elds (bin-sorted dense), then grab global tickets
#pragma unroll
    for (int j = 0; j < EPT; ++j) {
        if (bn[j] >= 0) {
            int pos = atomicAdd(&cur[bn[j]], 1);
            elds[pos] = wd[j];
        }
    }
    ticket[t] = (t < nbuck && h > 0) ? atomicAdd(&bcursor[t], h) : 0;
    __syncthreads();

    // copy-out: one wave per bin, contiguous LDS read + coalesced global write
    for (int b = wav; b < nbuck; b += 4) {
        int len = hist[b];
        int src = binstart[b];
        int tk  = ticket[b];
        unsigned* __restrict__ dst = bucket + (size_t)b * BCAP;
        for (int j = lane; j < len; j += 64) {
            int d = tk + j;
            if (d < BCAP) dst[d] = elds[src + j];
        }
    }
}

// level 2: one 512-thread workgroup per bucket (512 nodes, 1 node/thread).
// Bucket read ONCE into registers (20/thread, unrolled). Integrated prefix base
// (no scan_bsums launch). Wave-shfl scan (2 barriers instead of 18). LDS hist ->
// offsets+dinv; LDS cursor scatter into contiguous csr window.
__global__ void __launch_bounds__(512)
level2_csr(const unsigned* __restrict__ bucket, const int* __restrict__ bcursor,
           int nbuck, int n,
           int* __restrict__ offsets, float* __restrict__ dinv, int* __restrict__ csr) {
    __shared__ int hist[NPB];       // 512
    __shared__ int nodeoff[NPB];
    __shared__ int sred[NPB];
    __shared__ int wsum[8];
    int b = blockIdx.x;
    int t = threadIdx.x;            // 0..511, owns node nbeg+t
    int lane = t & 63, wav = t >> 6;
    int nbeg = b << BBITS;
    int cnt = min(bcursor[b], BCAP);

    // base = sum_{j<b} min(bcursor[j], BCAP)
    sred[t] = (t < b && t < nbuck) ? min(bcursor[t], BCAP) : 0;
    __syncthreads();
    for (int off = 256; off > 0; off >>= 1) {
        if (t < off) sred[t] += sred[t + off];
        __syncthreads();
    }
    int base = sred[0];
    if (b == nbuck - 1 && t == 0) offsets[n] = base + cnt;   // grand total

    // single global read of this bucket's edges into registers
    const unsigned* __restrict__ bk = bucket + (size_t)b * BCAP;
    unsigned ew[EPT2];
    int el[EPT2];
#pragma unroll
    for (int j = 0; j < EPT2; ++j) {
        int e = t + 512 * j;
        if (e < cnt) {
            unsigned w = bk[e];
            ew[j] = w;
            el[j] = (int)(w >> 17);
        } else {
            el[j] = -1;
        }
    }

    hist[t] = 0;
    __syncthreads();
#pragma unroll
    for (int j = 0; j < EPT2; ++j)
        if (el[j] >= 0) atomicAdd(&hist[el[j]], 1);
    __syncthreads();

    // exclusive scan of hist[512]: shfl within wave, 1 barrier across 8 waves
    int h = hist[t];
    int v = h;
    for (int off = 1; off < 64; off <<= 1) {
        int u = __shfl_up(v, off);
        if (lane >= off) v += u;
    }
    if (lane == 63) wsum[wav] = v;
    __syncthreads();
    int wbase = 0;
    for (int w2 = 0; w2 < wav; ++w2) wbase += wsum[w2];
    int p = base + wbase + v - h;                // exclusive offset for node nbeg+t
    nodeoff[t] = p;
    int node = nbeg + t;
    if (node < n) {
        offsets[node] = p;
        dinv[node] = rsqrtf((float)(h + 1));     // +1 self-loop; deg>=1 always
    }
    __syncthreads();
    hist[t] = 0;                                 // reuse as cursors
    __syncthreads();
#pragma unroll
    for (int j = 0; j < EPT2; ++j) {
        if (el[j] >= 0) {
            int l = el[j];
            int pos = nodeoff[l] + atomicAdd(&hist[l], 1);
            csr[pos] = (int)(ew[j] & 0x1FFFFu);
        }
    }
}

// ---------------- up-front projection: y[node][64] = dinv[node] * (x_row . W_col) ----------------
// A = W rows (M-tile per wave: outcols wave*16..+15), B = node rows (N = 16 nodes/block).
// D row=(lane>>4)*4+reg -> outcol, D col=lane&15 -> node  [m89-verified C/D layout].
// x is converted fp32->bf16 in an LDS tile (stride 68 dwords: 16B-aligned rows, 2-way banks = free).
__global__ void __launch_bounds__(256)
project_mfma(const void* __restrict__ xv, const unsigned* __restrict__ Wp,
             const float* __restrict__ dinv, unsigned* __restrict__ y,
             int n, const int* __restrict__ flags) {
    __shared__ unsigned xs[16][68];
    int t = threadIdx.x;
    int wave = t >> 6;               // outcol tile 0..3
    int lane = t & 63;
    int m16  = lane & 15;
    int quad = lane >> 4;
    int row0 = blockIdx.x * 16;
    if (row0 >= n) return;
    int fx = flags[0];

    // stage 16 node rows as packed bf16 into LDS (converted once, shared by 4 waves)
    for (int idx = t; idx < 16 * 64; idx += 256) {
        int r = idx >> 6, p = idx & 63;
        int node = min(row0 + r, n - 1);
        unsigned w;
        if (fx) {
            w = ((const unsigned*)xv)[(size_t)node * 64 + p];
        } else {
            float2 v = ((const float2*)xv)[(size_t)node * 64 + p];
            w = pack2bf(v.x, v.y);
        }
        xs[r][p] = w;
    }
    __syncthreads();

    const uint4* __restrict__ Arow = (const uint4*)(Wp + (size_t)(wave * 16 + m16) * 64);
    floatx4 acc = {0.f, 0.f, 0.f, 0.f};
#pragma unroll
    for (int kc = 0; kc < 4; ++kc) {
        union { uint4 u; short8 s; } a, b;
        a.u = Arow[kc * 4 + quad];
        b.u = *(const uint4*)&xs[m16][(kc * 4 + quad) * 4];
        acc = __builtin_amdgcn_mfma_f32_16x16x32_bf16(a.s, b.s, acc, 0, 0, 0);
    }
    int node = row0 + m16;
    if (node < n) {
        float di = dinv[node];
        uint2 w;
        w.x = pack2bf(di * acc[0], di * acc[1]);
        w.y = pack2bf(di * acc[2], di * acc[3]);
        *(uint2*)(y + (size_t)node * 32 + wave * 8 + quad * 2) = w;   // outcols wave*16+quad*4..+3
    }
}

// ---------------- propagation on 64-feat pre-scaled rows (R5-measured-best, 51.7us/hop) ----------------
// g[j] = dinv[j]*h[j] is stored; per hop: sum_{j in N(i)+self} g[j], then
//   mode 0: g_out = di^2 * sum (bf16)      mode 1: h_out = di*sum + b (fp32 to d_out, nt)
// wave = 1 node; 16 lanes = 1 edge (uint2/lane = 128B row) -> 4 edge-groups/wave,
// unroll x4 => 16 gathers in flight. At the miss-concurrency floor (R6/R7 analysis).
__global__ void __launch_bounds__(256)
propagate64(const unsigned* __restrict__ hin, const int* __restrict__ offsets,
            const int* __restrict__ csr, const float* __restrict__ dinv,
            void* __restrict__ outv, const void* __restrict__ bv,
            int n, int mode, const int* __restrict__ flags) {
    int wave = threadIdx.x >> 6;
    int lane = threadIdx.x & 63;
    int g    = lane >> 4;            // edge-group 0..3
    int s    = lane & 15;            // dword pair within row (dwords 2s, 2s+1 = feats 4s..4s+3)
    int i = blockIdx.x * 4 + wave;
    if (i >= n) return;
    int beg = offsets[i];
    int end = offsets[i + 1];
    // self row: issue early, same addr across groups (broadcast-friendly)
    uint2 ps = *(const uint2*)(hin + (size_t)i * 32 + 2 * s);
    float a0 = 0.f, a1 = 0.f, a2 = 0.f, a3 = 0.f;
    int k = beg + g;
    for (; k + 12 < end; k += 16) {          // 16 edges per wave per round
        int s0 = csr[k], s1 = csr[k + 4], s2 = csr[k + 8], s3 = csr[k + 12];
        uint2 p0 = *(const uint2*)(hin + (size_t)s0 * 32 + 2 * s);
        uint2 p1 = *(const uint2*)(hin + (size_t)s1 * 32 + 2 * s);
        uint2 p2 = *(const uint2*)(hin + (size_t)s2 * 32 + 2 * s);
        uint2 p3 = *(const uint2*)(hin + (size_t)s3 * 32 + 2 * s);
        a0 += bflo(p0.x); a1 += bfhi(p0.x); a2 += bflo(p0.y); a3 += bfhi(p0.y);
        a0 += bflo(p1.x); a1 += bfhi(p1.x); a2 += bflo(p1.y); a3 += bfhi(p1.y);
        a0 += bflo(p2.x); a1 += bfhi(p2.x); a2 += bflo(p2.y); a3 += bfhi(p2.y);
        a0 += bflo(p3.x); a1 += bfhi(p3.x); a2 += bflo(p3.y); a3 += bfhi(p3.y);
    }
    for (; k < end; k += 4) {
        int sj = csr[k];
        uint2 p = *(const uint2*)(hin + (size_t)sj * 32 + 2 * s);
        a0 += bflo(p.x); a1 += bfhi(p.x); a2 += bflo(p.y); a3 += bfhi(p.y);
    }
    if (g == 0) {                    // self-loop term counted exactly once
        a0 += bflo(ps.x); a1 += bfhi(ps.x); a2 += bflo(ps.y); a3 += bfhi(ps.y);
    }
    // reduce across the 4 edge-groups
    a0 += __shfl_xor(a0, 16); a1 += __shfl_xor(a1, 16);
    a2 += __shfl_xor(a2, 16); a3 += __shfl_xor(a3, 16);
    a0 += __shfl_xor(a0, 32); a1 += __shfl_xor(a1, 32);
    a2 += __shfl_xor(a2, 32); a3 += __shfl_xor(a3, 32);
    if (g == 0) {
        float di = dinv[i];
        if (mode == 0) {
            float sc = di * di;
            uint2 w;
            w.x = pack2bf(sc * a0, sc * a1);
            w.y = pack2bf(sc * a2, sc * a3);
            *(uint2*)((unsigned*)outv + (size_t)i * 32 + 2 * s) = w;
        } else {
            float b0, b1, b2, b3;
            if (flags[2]) {
                const unsigned short* bp = (const unsigned short*)bv;
                union { unsigned u; float f; } c0, c1, c2, c3;
                c0.u = (unsigned)bp[4 * s]     << 16;
                c1.u = (unsigned)bp[4 * s + 1] << 16;
                c2.u = (unsigned)bp[4 * s + 2] << 16;
                c3.u = (unsigned)bp[4 * s + 3] << 16;
                b0 = c0.f; b1 = c1.f; b2 = c2.f; b3 = c3.f;
            } else {
                float4 bb = ((const float4*)bv)[s];
                b0 = bb.x; b1 = bb.y; b2 = bb.z; b3 = bb.w;
            }
            floatx4 o;
            o[0] = di * a0 + b0;
            o[1] = di * a1 + b1;
            o[2] = di * a2 + b2;
            o[3] = di * a3 + b3;
            // final output is never re-read: keep it out of L2 while this hop gathers
            __builtin_nontemporal_store(o, (floatx4*)outv + (size_t)i * 16 + s);
        }
    }
}

// ---------------- launch ----------------

extern "C" void kernel_launch(void* const* d_in, const int* in_sizes, int n_in,
                              void* d_out, int out_size, void* d_ws, size_t ws_size,
                              hipStream_t stream) {
    const void* x  = d_in[0];
    const int*  ei = (const int*)d_in[1];
    const void* W  = d_in[2];
    const void* b  = d_in[3];
    float* out = (float*)d_out;              // fp32 output

    const int n = in_sizes[0] / FEAT;        // 100000
    const int E = in_sizes[1] / 2;           // 1600000
    const int nbuck = (n + NPB - 1) >> BBITS;   // 196 <= 256

    // workspace layout (256B-aligned slabs)
    char* ws = (char*)d_ws;
    size_t off = 0;
    auto alloc = [&](size_t bytes) {
        void* p = ws + off;
        off = (off + bytes + 255) & ~(size_t)255;
        return p;
    };
    unsigned* y       = (unsigned*)alloc((size_t)n * 32 * sizeof(unsigned));  // 64-feat bf16 rows
    unsigned* hA      = (unsigned*)alloc((size_t)n * 32 * sizeof(unsigned));
    unsigned* Wp      = (unsigned*)alloc((size_t)OUTF * (FEAT / 2) * sizeof(unsigned));
    int*      offsets = (int*)alloc((size_t)(n + 1) * sizeof(int));
    float*    dinv    = (float*)alloc((size_t)n * sizeof(float));
    int*      csr     = (int*)alloc((size_t)E * sizeof(int));
    unsigned* bucket  = (unsigned*)alloc((size_t)nbuck * BCAP * sizeof(unsigned));
    int*      bcursor = (int*)alloc((size_t)nbuck * sizeof(int));
    int*      flags   = (int*)alloc(3 * sizeof(int));

    // dtype sniff + bcursor zero + W->bf16 (one launch; graph-safe)
    sniff_convw<<<1, 256, 0, stream>>>((const unsigned*)x, (const unsigned*)ei,
                                       W, Wp, flags, bcursor, nbuck);

    // CSR build: LDS-binned two-level (single-read register staging both levels)
    level1_bin<<<(E + L1_CHUNK - 1) / L1_CHUNK, 256, 0, stream>>>(ei, E, bcursor, bucket,
                                                                  flags, nbuck);
    level2_csr<<<nbuck, 512, 0, stream>>>(bucket, bcursor, nbuck, n, offsets, dinv, csr);

    // project first: y = dinv * (x @ W^T)   [(A^3 x) W^T == A^3 (x W^T)]
    project_mfma<<<(n + 15) / 16, 256, 0, stream>>>(x, Wp, dinv, y, n, flags);

    // 3 hops on 64-feat rows: y -> hA -> y -> out (last hop adds bias, writes fp32 nt)
    const int propBlocks = (n + 3) / 4;      // 4 waves/block, 1 node/wave
    propagate64<<<propBlocks, 256, 0, stream>>>(y,  offsets, csr, dinv, hA,  b, n, 0, flags);
    propagate64<<<propBlocks, 256, 0, stream>>>(hA, offsets, csr, dinv, y,   b, n, 0, flags);
    propagate64<<<propBlocks, 256, 0, stream>>>(y,  offsets, csr, dinv, out, b, n, 1, flags);
}

// Round 10
// 298.951 us; speedup vs baseline: 1.0875x; 1.0342x over previous
//
#include <hip/hip_runtime.h>
#include <hip/hip_bf16.h>

#define FEAT 128
#define OUTF 64
#define BBITS 9           // nodes per bucket = 512
#define NPB (1 << BBITS)
#define NBIN 256          // level-1 hist arrays (nbuck = 196 <= 256)
#define BCAP 10240        // mean 8163 edges/bucket, sigma ~90 -> +23 sigma
#define L1_CHUNK 4096
#define EPT 16            // edges per thread in level1 (L1_CHUNK / 256)
#define CSTR 32           // bcursor stride in ints: one counter per 128B line (anti-serialization)

typedef __attribute__((ext_vector_type(8))) short short8;   // 8 bf16 = 4 VGPRs (MFMA A/B frag)
typedef __attribute__((ext_vector_type(4))) float floatx4;  // MFMA C/D frag (nt-store safe)

// ---- bf16 helpers (packed pair in a 32-bit word, little-endian: lo16 = even elem) ----
__device__ inline float bflo(unsigned p) { union { unsigned u; float f; } c; c.u = p << 16;        return c.f; }
__device__ inline float bfhi(unsigned p) { union { unsigned u; float f; } c; c.u = p & 0xffff0000u; return c.f; }
__device__ inline unsigned rne16(float v) {   // fp32 -> bf16 bits, round-nearest-even
    union { float f; unsigned u; } c; c.f = v;
    return (c.u + 0x7fffu + ((c.u >> 16) & 1u)) >> 16;
}
__device__ inline unsigned pack2bf(float a, float b) { return rne16(a) | (rne16(b) << 16); }

// ---------------- dtype sniff + bcursor zero + W conversion (one launch) ----------------
// flags[0]=1 iff x is packed bf16; flags[1]=1 iff edge_index is int64; flags[2]=1 iff W is packed bf16.
__global__ void sniff_convw(const unsigned* __restrict__ x, const unsigned* __restrict__ ei,
                            const void* __restrict__ Wv, unsigned* __restrict__ Wp,
                            int* __restrict__ flags, int* __restrict__ bcursor, int nbuck) {
    __shared__ int s_x, s_z, s_w;
    int t = threadIdx.x;
    if (t == 0) { s_x = 0; s_z = 0; s_w = 0; }
    __syncthreads();
    if (t < nbuck) bcursor[t * CSTR] = 0;     // line-strided counters
    unsigned lx = x[t] & 0xffffu;
    unsigned ex = (lx >> 7) & 0xffu;
    if (lx == 0u || (ex >= 100u && ex <= 140u)) atomicAdd(&s_x, 1);
    unsigned lw = ((const unsigned*)Wv)[t] & 0xffffu;
    unsigned ew = (lw >> 7) & 0xffu;
    if (lw == 0u || (ew >= 100u && ew <= 140u)) atomicAdd(&s_w, 1);
    if (ei[2 * t + 1] == 0u) atomicAdd(&s_z, 1);
    __syncthreads();
    int wbf = (s_w >= 230);
    if (t == 0) {
        flags[0] = (s_x >= 230) ? 1 : 0;
        flags[1] = (s_z >= 250) ? 1 : 0;
        flags[2] = wbf;
    }
    // convert W -> packed bf16 (64x128 = 4096 pairs, 16 per thread)
    for (int idx = t; idx < OUTF * FEAT / 2; idx += 256) {
        if (wbf) {
            Wp[idx] = ((const unsigned*)Wv)[idx];
        } else {
            float2 v = ((const float2*)Wv)[idx];
            Wp[idx] = pack2bf(v.x, v.y);
        }
    }
}

__device__ inline int edge_row(const int* __restrict__ ei, int E, int e, int w64) {
    return w64 ? ei[2 * e] : ei[e];
}
__device__ inline int edge_col(const int* __restrict__ ei, int E, int e, int w64) {
    return w64 ? ei[2 * (E + e)] : ei[E + e];
}

// ---------------- CSR build: two-level, LDS-binned (R5-measured-best bodies) ----------------
// level 1: chunk of 4096 edges per block, loaded ONCE into registers (16/thread,
// fully unrolled -> VGPRs), LDS bin-sort by (dst>>9), dense copy-out via ebin.
// Tickets hit LINE-STRIDED global counters (R8 post-mortem: 77K atomics on 7 cache
// lines serialized at TCC; striding spreads them over 196 lines).
__global__ void __launch_bounds__(256)
level1_bin(const int* __restrict__ ei, int E, int* __restrict__ bcursor,
           unsigned* __restrict__ bucket, const int* __restrict__ flags, int nbuck) {
    __shared__ unsigned elds[L1_CHUNK];
    __shared__ unsigned char ebin[L1_CHUNK];
    __shared__ int hist[NBIN], binstart[NBIN], cur[NBIN], ticket[NBIN];
    int t = threadIdx.x;
    int base = blockIdx.x * L1_CHUNK;
    int cnt = min(E - base, L1_CHUNK);
    int w64 = flags[1];

    // single global read of this chunk's edges into registers
    unsigned wd[EPT];
    int bn[EPT];
#pragma unroll
    for (int j = 0; j < EPT; ++j) {
        int k = t + 256 * j;
        if (k < cnt) {
            int e = base + k;
            int c = edge_col(ei, E, e, w64);
            int r = edge_row(ei, E, e, w64);
            wd[j] = ((unsigned)(c & (NPB - 1)) << 17) | (unsigned)r;
            bn[j] = c >> BBITS;
        } else {
            bn[j] = -1;
        }
    }

    hist[t] = 0;
    __syncthreads();
#pragma unroll
    for (int j = 0; j < EPT; ++j)
        if (bn[j] >= 0) atomicAdd(&hist[bn[j]], 1);
    __syncthreads();
    binstart[t] = hist[t];
    __syncthreads();
    for (int off = 1; off < NBIN; off <<= 1) {
        int v = (t >= off) ? binstart[t - off] : 0;
        __syncthreads();
        binstart[t] += v;
        __syncthreads();
    }
    { int ex = binstart[t] - hist[t]; cur[t] = ex; binstart[t] = ex; }
    __syncthreads();
#pragma unroll
    for (int j = 0; j < EPT; ++j) {
        if (bn[j] >= 0) {
            int pos = atomicAdd(&cur[bn[j]], 1);
            elds[pos] = wd[j];
            ebin[pos] = (unsigned char)bn[j];
        }
    }
    __syncthreads();
    {
        int h = hist[t];
        ticket[t] = (t < nbuck && h > 0) ? atomicAdd(&bcursor[t * CSTR], h) : 0;
    }
    __syncthreads();
    for (int k = t; k < cnt; k += 256) {
        unsigned w = elds[k];
        int b = ebin[k];
        int dst = ticket[b] + (k - binstart[b]);
        if (dst < BCAP) bucket[(size_t)b * BCAP + dst] = w;
    }
}

// level 2: one 512-thread workgroup per bucket (512 nodes, 1 node/thread).
// Integrated prefix base (no scan_bsums launch); LDS hist -> offsets+dinv; LDS
// cursor scatter into contiguous csr window. (R6-measured body + strided bcursor.)
__global__ void __launch_bounds__(512)
level2_csr(const unsigned* __restrict__ bucket, const int* __restrict__ bcursor,
           int nbuck, int n,
           int* __restrict__ offsets, float* __restrict__ dinv, int* __restrict__ csr) {
    __shared__ int hist[NPB];       // 512
    __shared__ int nodeoff[NPB];
    __shared__ int sdata[NPB];
    int b = blockIdx.x;
    int t = threadIdx.x;            // 0..511, owns node nbeg+t
    int nbeg = b << BBITS;
    int cnt = min(bcursor[b * CSTR], BCAP);

    // base = sum_{j<b} min(bcursor[j*CSTR], BCAP)
    sdata[t] = (t < b && t < nbuck) ? min(bcursor[t * CSTR], BCAP) : 0;
    __syncthreads();
    for (int off = 256; off > 0; off >>= 1) {
        if (t < off) sdata[t] += sdata[t + off];
        __syncthreads();
    }
    int base = sdata[0];
    __syncthreads();
    if (b == nbuck - 1 && t == 0) offsets[n] = base + cnt;   // grand total

    const unsigned* __restrict__ bk = bucket + (size_t)b * BCAP;

    hist[t] = 0;
    __syncthreads();
    for (int e = t; e < cnt; e += 512) atomicAdd(&hist[bk[e] >> 17], 1);
    __syncthreads();
    int h = hist[t];
    sdata[t] = h;
    __syncthreads();
    for (int off = 1; off < NPB; off <<= 1) {
        int v = (t >= off) ? sdata[t - off] : 0;
        __syncthreads();
        sdata[t] += v;
        __syncthreads();
    }
    int p = base + sdata[t] - h;                 // exclusive offset for node nbeg+t
    nodeoff[t] = p;
    int node = nbeg + t;
    if (node < n) {
        offsets[node] = p;
        dinv[node] = rsqrtf((float)(h + 1));     // +1 self-loop; deg>=1 always
    }
    __syncthreads();
    hist[t] = 0;                                 // reuse as cursors
    __syncthreads();
    for (int e = t; e < cnt; e += 512) {
        unsigned w = bk[e];
        int l = w >> 17;
        int pos = nodeoff[l] + atomicAdd(&hist[l], 1);
        csr[pos] = (int)(w & 0x1FFFFu);
    }
}

// ---------------- up-front projection: y[node][64] = dinv[node] * (x_row . W_col) ----------------
// A = W rows (M-tile per wave: outcols wave*16..+15), B = node rows (N = 16 nodes/block).
// D row=(lane>>4)*4+reg -> outcol, D col=lane&15 -> node  [m89-verified C/D layout].
// x is converted fp32->bf16 in an LDS tile (stride 68 dwords: 16B-aligned rows, 2-way banks = free).
__global__ void __launch_bounds__(256)
project_mfma(const void* __restrict__ xv, const unsigned* __restrict__ Wp,
             const float* __restrict__ dinv, unsigned* __restrict__ y,
             int n, const int* __restrict__ flags) {
    __shared__ unsigned xs[16][68];
    int t = threadIdx.x;
    int wave = t >> 6;               // outcol tile 0..3
    int lane = t & 63;
    int m16  = lane & 15;
    int quad = lane >> 4;
    int row0 = blockIdx.x * 16;
    if (row0 >= n) return;
    int fx = flags[0];

    // stage 16 node rows as packed bf16 into LDS (converted once, shared by 4 waves)
    for (int idx = t; idx < 16 * 64; idx += 256) {
        int r = idx >> 6, p = idx & 63;
        int node = min(row0 + r, n - 1);
        unsigned w;
        if (fx) {
            w = ((const unsigned*)xv)[(size_t)node * 64 + p];
        } else {
            float2 v = ((const float2*)xv)[(size_t)node * 64 + p];
            w = pack2bf(v.x, v.y);
        }
        xs[r][p] = w;
    }
    __syncthreads();

    const uint4* __restrict__ Arow = (const uint4*)(Wp + (size_t)(wave * 16 + m16) * 64);
    floatx4 acc = {0.f, 0.f, 0.f, 0.f};
#pragma unroll
    for (int kc = 0; kc < 4; ++kc) {
        union { uint4 u; short8 s; } a, b;
        a.u = Arow[kc * 4 + quad];
        b.u = *(const uint4*)&xs[m16][(kc * 4 + quad) * 4];
        acc = __builtin_amdgcn_mfma_f32_16x16x32_bf16(a.s, b.s, acc, 0, 0, 0);
    }
    int node = row0 + m16;
    if (node < n) {
        float di = dinv[node];
        uint2 w;
        w.x = pack2bf(di * acc[0], di * acc[1]);
        w.y = pack2bf(di * acc[2], di * acc[3]);
        *(uint2*)(y + (size_t)node * 32 + wave * 8 + quad * 2) = w;   // outcols wave*16+quad*4..+3
    }
}

// ---------------- propagation on 64-feat pre-scaled rows (R5-measured-best, 51.5us/hop) ----------------
// g[j] = dinv[j]*h[j] is stored; per hop: sum_{j in N(i)+self} g[j], then
//   mode 0: g_out = di^2 * sum (bf16)      mode 1: h_out = di*sum + b (fp32 to d_out, nt)
// wave = 1 node; 16 lanes = 1 edge (uint2/lane = 128B row) -> 4 edge-groups/wave,
// unroll x4 => 16 gathers in flight. At the miss-concurrency floor (R2/R3/R6 all failed to move it).
__global__ void __launch_bounds__(256)
propagate64(const unsigned* __restrict__ hin, const int* __restrict__ offsets,
            const int* __restrict__ csr, const float* __restrict__ dinv,
            void* __restrict__ outv, const void* __restrict__ bv,
            int n, int mode, const int* __restrict__ flags) {
    int wave = threadIdx.x >> 6;
    int lane = threadIdx.x & 63;
    int g    = lane >> 4;            // edge-group 0..3
    int s    = lane & 15;            // dword pair within row (dwords 2s, 2s+1 = feats 4s..4s+3)
    int i = blockIdx.x * 4 + wave;
    if (i >= n) return;
    int beg = offsets[i];
    int end = offsets[i + 1];
    // self row: issue early, same addr across groups (broadcast-friendly)
    uint2 ps = *(const uint2*)(hin + (size_t)i * 32 + 2 * s);
    float a0 = 0.f, a1 = 0.f, a2 = 0.f, a3 = 0.f;
    int k = beg + g;
    for (; k + 12 < end; k += 16) {          // 16 edges per wave per round
        int s0 = csr[k], s1 = csr[k + 4], s2 = csr[k + 8], s3 = csr[k + 12];
        uint2 p0 = *(const uint2*)(hin + (size_t)s0 * 32 + 2 * s);
        uint2 p1 = *(const uint2*)(hin + (size_t)s1 * 32 + 2 * s);
        uint2 p2 = *(const uint2*)(hin + (size_t)s2 * 32 + 2 * s);
        uint2 p3 = *(const uint2*)(hin + (size_t)s3 * 32 + 2 * s);
        a0 += bflo(p0.x); a1 += bfhi(p0.x); a2 += bflo(p0.y); a3 += bfhi(p0.y);
        a0 += bflo(p1.x); a1 += bfhi(p1.x); a2 += bflo(p1.y); a3 += bfhi(p1.y);
        a0 += bflo(p2.x); a1 += bfhi(p2.x); a2 += bflo(p2.y); a3 += bfhi(p2.y);
        a0 += bflo(p3.x); a1 += bfhi(p3.x); a2 += bflo(p3.y); a3 += bfhi(p3.y);
    }
    for (; k < end; k += 4) {
        int sj = csr[k];
        uint2 p = *(const uint2*)(hin + (size_t)sj * 32 + 2 * s);
        a0 += bflo(p.x); a1 += bfhi(p.x); a2 += bflo(p.y); a3 += bfhi(p.y);
    }
    if (g == 0) {                    // self-loop term counted exactly once
        a0 += bflo(ps.x); a1 += bfhi(ps.x); a2 += bflo(ps.y); a3 += bfhi(ps.y);
    }
    // reduce across the 4 edge-groups
    a0 += __shfl_xor(a0, 16); a1 += __shfl_xor(a1, 16);
    a2 += __shfl_xor(a2, 16); a3 += __shfl_xor(a3, 16);
    a0 += __shfl_xor(a0, 32); a1 += __shfl_xor(a1, 32);
    a2 += __shfl_xor(a2, 32); a3 += __shfl_xor(a3, 32);
    if (g == 0) {
        float di = dinv[i];
        if (mode == 0) {
            float sc = di * di;
            uint2 w;
            w.x = pack2bf(sc * a0, sc * a1);
            w.y = pack2bf(sc * a2, sc * a3);
            *(uint2*)((unsigned*)outv + (size_t)i * 32 + 2 * s) = w;
        } else {
            float b0, b1, b2, b3;
            if (flags[2]) {
                const unsigned short* bp = (const unsigned short*)bv;
                union { unsigned u; float f; } c0, c1, c2, c3;
                c0.u = (unsigned)bp[4 * s]     << 16;
                c1.u = (unsigned)bp[4 * s + 1] << 16;
                c2.u = (unsigned)bp[4 * s + 2] << 16;
                c3.u = (unsigned)bp[4 * s + 3] << 16;
                b0 = c0.f; b1 = c1.f; b2 = c2.f; b3 = c3.f;
            } else {
                float4 bb = ((const float4*)bv)[s];
                b0 = bb.x; b1 = bb.y; b2 = bb.z; b3 = bb.w;
            }
            floatx4 o;
            o[0] = di * a0 + b0;
            o[1] = di * a1 + b1;
            o[2] = di * a2 + b2;
            o[3] = di * a3 + b3;
            // final output is never re-read: keep it out of L2 while this hop gathers
            __builtin_nontemporal_store(o, (floatx4*)outv + (size_t)i * 16 + s);
        }
    }
}

// ---------------- launch ----------------

extern "C" void kernel_launch(void* const* d_in, const int* in_sizes, int n_in,
                              void* d_out, int out_size, void* d_ws, size_t ws_size,
                              hipStream_t stream) {
    const void* x  = d_in[0];
    const int*  ei = (const int*)d_in[1];
    const void* W  = d_in[2];
    const void* b  = d_in[3];
    float* out = (float*)d_out;              // fp32 output

    const int n = in_sizes[0] / FEAT;        // 100000
    const int E = in_sizes[1] / 2;           // 1600000
    const int nbuck = (n + NPB - 1) >> BBITS;   // 196 <= 256

    // workspace layout (256B-aligned slabs)
    char* ws = (char*)d_ws;
    size_t off = 0;
    auto alloc = [&](size_t bytes) {
        void* p = ws + off;
        off = (off + bytes + 255) & ~(size_t)255;
        return p;
    };
    unsigned* y       = (unsigned*)alloc((size_t)n * 32 * sizeof(unsigned));  // 64-feat bf16 rows
    unsigned* hA      = (unsigned*)alloc((size_t)n * 32 * sizeof(unsigned));
    unsigned* Wp      = (unsigned*)alloc((size_t)OUTF * (FEAT / 2) * sizeof(unsigned));
    int*      offsets = (int*)alloc((size_t)(n + 1) * sizeof(int));
    float*    dinv    = (float*)alloc((size_t)n * sizeof(float));
    int*      csr     = (int*)alloc((size_t)E * sizeof(int));
    unsigned* bucket  = (unsigned*)alloc((size_t)nbuck * BCAP * sizeof(unsigned));
    int*      bcursor = (int*)alloc((size_t)nbuck * CSTR * sizeof(int));   // line-strided
    int*      flags   = (int*)alloc(3 * sizeof(int));

    // dtype sniff + bcursor zero + W->bf16 (one launch; graph-safe)
    sniff_convw<<<1, 256, 0, stream>>>((const unsigned*)x, (const unsigned*)ei,
                                       W, Wp, flags, bcursor, nbuck);

    // CSR build: LDS-binned two-level (R5 bodies; line-strided ticket counters)
    level1_bin<<<(E + L1_CHUNK - 1) / L1_CHUNK, 256, 0, stream>>>(ei, E, bcursor, bucket,
                                                                  flags, nbuck);
    level2_csr<<<nbuck, 512, 0, stream>>>(bucket, bcursor, nbuck, n, offsets, dinv, csr);

    // project first: y = dinv * (x @ W^T)   [(A^3 x) W^T == A^3 (x W^T)]
    project_mfma<<<(n + 15) / 16, 256, 0, stream>>>(x, Wp, dinv, y, n, flags);

    // 3 hops on 64-feat rows: y -> hA -> y -> out (last hop adds bias, writes fp32 nt)
    const int propBlocks = (n + 3) / 4;      // 4 waves/block, 1 node/wave
    propagate64<<<propBlocks, 256, 0, stream>>>(y,  offsets, csr, dinv, hA,  b, n, 0, flags);
    propagate64<<<propBlocks, 256, 0, stream>>>(hA, offsets, csr, dinv, y,   b, n, 0, flags);
    propagate64<<<propBlocks, 256, 0, stream>>>(y,  offsets, csr, dinv, out, b, n, 1, flags);
}